// Round 11
// baseline (4953.746 us; speedup 1.0000x reference)
//
#include <hip/hip_runtime.h>

// ---------------------------------------------------------------------------
// LinearDecoder: MLP encoder -> 64-step LSTM decoder with softmax/sigmoid head
// B=8192, LAT=256, MLP=512, HID=512, INP=128, T=64, gates N=2048, K=640
// R8 macro-structure (verified): per-step gate + head256, lockstep.
// R11: gate merged to ONE barrier pair per K-tile (10 phases, 64-MFMA
// clusters). Guard discipline: tile p's readiness guaranteed by phase p-1's
// pre-ENDBAR vmcnt(8); stages issued post-lgkm-drain (WAR margin ~+300cyc,
// pattern validated in R10).
// ---------------------------------------------------------------------------

typedef _Float16 h16;
typedef __attribute__((ext_vector_type(8))) _Float16 f16x8;
typedef __attribute__((ext_vector_type(4))) float f32x4;

#define BB 8192
#define TT 64

__device__ __forceinline__ void gload16(const void* g, void* lds) {
  __builtin_amdgcn_global_load_lds(
      (const __attribute__((address_space(1))) unsigned int*)g,
      (__attribute__((address_space(3))) unsigned int*)lds, 16, 0, 0);
}

__device__ __forceinline__ float sigm(float x) { return 1.f / (1.f + __expf(-x)); }
__device__ __forceinline__ float tanhf_(float x) { return 2.f / (1.f + __expf(-2.f * x)) - 1.f; }

#define MIDBAR_LG()                                        \
  do {                                                     \
    __builtin_amdgcn_s_barrier();                          \
    asm volatile("s_waitcnt lgkmcnt(0)" ::: "memory");     \
    __builtin_amdgcn_sched_barrier(0);                     \
  } while (0)
#define ENDBAR()                                           \
  do {                                                     \
    __builtin_amdgcn_s_barrier();                          \
    asm volatile("" ::: "memory");                         \
  } while (0)

// ---------------------------------------------------------------------------
// gate2: 256x256 gate GEMM, ONE barrier pair per K-tile + fused LSTM cell.
// A = XH [8192][640] fp16; Bt = WgT [2048][640] (permuted); K=640 (10 K-tiles).
// Gate col permutation: n' = by*256 + wc*64 + q*16 + jj
//                       orig = q*512 + (by*64 + wc*16 + jj)
// Per phase p (slot s=p&1): readAll(tile p) | MIDBAR | stage tile p+2 -> s |
//                           64 MFMA | vmcnt(8) [tile p+1 landed] | ENDBAR
// ---------------------------------------------------------------------------
__global__ __launch_bounds__(512, 2) void gate2(
    const h16* __restrict__ A, const h16* __restrict__ Bt,
    const float* __restrict__ bg, float* __restrict__ Cbuf,
    h16* __restrict__ Hout) {
  __shared__ __align__(16) h16 As[2][16384];
  __shared__ __align__(16) h16 Bs[2][16384];
  const int tid = threadIdx.x;
  const int lane = tid & 63;
  const int wid = tid >> 6;
  const int wr = wid >> 2, wc = wid & 3;
  const int m0 = blockIdx.x * 256;
  const int n0 = blockIdx.y * 256;
  const int arow = lane & 15, khi = lane >> 4;
  const int x7 = arow & 7;

  auto stage = [&](h16(*dst)[16384], int slot, int h, const h16* src, int base,
                   int kt) {
#pragma unroll
    for (int li = 0; li < 2; ++li) {
      int rowbase = li * 128 + h * 64 + wid * 8;  // wave-uniform
      int row = rowbase + (lane >> 3);
      int gc = (lane & 7) ^ (lane >> 3);
      gload16(src + (size_t)(base + row) * 640 + kt * 64 + gc * 8,
              &dst[slot][rowbase * 64]);
    }
  };
  // stage a full K-tile (B h0,h1 then A h0,h1 = 8 loads)
  auto stageTile = [&](int slot, int kt) {
    stage(Bs, slot, 0, Bt, n0, kt);
    stage(Bs, slot, 1, Bt, n0, kt);
    stage(As, slot, 0, A, m0, kt);
    stage(As, slot, 1, A, m0, kt);
  };

  f32x4 acc[8][4];
#pragma unroll
  for (int i = 0; i < 8; ++i)
#pragma unroll
    for (int jj = 0; jj < 4; ++jj) acc[i][jj] = (f32x4)0.f;
  f16x8 af[2][2][4];  // [ms][ks][mr]
  f16x8 bf[2][4];     // [ks][jj]

  auto readAll = [&](int slot) {
#pragma unroll
    for (int ks = 0; ks < 2; ++ks)
#pragma unroll
      for (int jj = 0; jj < 4; ++jj) {
        int rb = wc * 64 + jj * 16 + arow;
        bf[ks][jj] = *(const f16x8*)&Bs[slot][rb * 64 + ((ks * 4 + khi) ^ x7) * 8];
      }
#pragma unroll
    for (int ms = 0; ms < 2; ++ms)
#pragma unroll
      for (int ks = 0; ks < 2; ++ks)
#pragma unroll
        for (int mr = 0; mr < 4; ++mr) {
          int r = wr * 128 + ms * 64 + mr * 16 + arow;
          af[ms][ks][mr] =
              *(const f16x8*)&As[slot][r * 64 + ((ks * 4 + khi) ^ x7) * 8];
        }
  };
  auto mfma64 = [&]() {
    __builtin_amdgcn_s_setprio(1);
#pragma unroll
    for (int ms = 0; ms < 2; ++ms)
#pragma unroll
      for (int ks = 0; ks < 2; ++ks)
#pragma unroll
        for (int mr = 0; mr < 4; ++mr)
#pragma unroll
          for (int jj = 0; jj < 4; ++jj)
            acc[ms * 4 + mr][jj] = __builtin_amdgcn_mfma_f32_16x16x32_f16(
                af[ms][ks][mr], bf[ks][jj], acc[ms * 4 + mr][jj], 0, 0, 0);
    __builtin_amdgcn_s_setprio(0);
  };

  // prologue: tiles 0 and 1
  stageTile(0, 0);
  stageTile(1, 1);
  asm volatile("s_waitcnt vmcnt(8)" ::: "memory");  // tile0 landed
  ENDBAR();

#pragma unroll 1
  for (int i = 0; i < 5; ++i) {
    // phase p=2i, slot0: consume tile 2i
    readAll(0);
    MIDBAR_LG();
    if (i < 4) stageTile(0, 2 * i + 2);
    mfma64();
    if (i < 4)
      asm volatile("s_waitcnt vmcnt(8)" ::: "memory");  // tile 2i+1 landed
    else
      asm volatile("s_waitcnt vmcnt(0)" ::: "memory");  // tile 9 landed
    ENDBAR();
    // phase p=2i+1, slot1: consume tile 2i+1
    readAll(1);
    MIDBAR_LG();
    if (i < 4) stageTile(1, 2 * i + 3);
    mfma64();
    if (i < 4)
      asm volatile("s_waitcnt vmcnt(8)" ::: "memory");  // tile 2i+2 landed
    else
      asm volatile("s_waitcnt vmcnt(0)" ::: "memory");
    ENDBAR();
  }

  // ---- gate epilogue: LSTM cell update ----
  const int nb = n0 + wc * 64;
  const float bI = bg[nb + arow];
  const float bF = bg[nb + 16 + arow];
  const float bG = bg[nb + 32 + arow];
  const float bO = bg[nb + 48 + arow];
  const int hj = blockIdx.y * 64 + wc * 16 + arow;
#pragma unroll
  for (int mrep = 0; mrep < 8; ++mrep) {
#pragma unroll
    for (int r = 0; r < 4; ++r) {
      int m = m0 + wr * 128 + mrep * 16 + khi * 4 + r;
      float gi = sigm(acc[mrep][0][r] + bI);
      float gf = sigm(acc[mrep][1][r] + bF);
      float gg = tanhf_(acc[mrep][2][r] + bG);
      float go = sigm(acc[mrep][3][r] + bO);
      size_t ci = (size_t)m * 512 + hj;
      float c2 = gf * Cbuf[ci] + gi * gg;
      Cbuf[ci] = c2;
      Hout[(size_t)m * 640 + 128 + hj] = (h16)(go * tanhf_(c2));
    }
  }
}

// ---------------------------------------------------------------------------
// head256: full-machine head. 256 blocks x 32 rows, 256 thr (4 waves).
// Verified R8 kernel. swz aligns block's XCD with h-writer XCD (mx%8).
// ---------------------------------------------------------------------------
__global__ __launch_bounds__(256) void head256(
    const h16* __restrict__ A, int lda, const h16* __restrict__ Bt,
    const float* __restrict__ bias, int nkt, h16* __restrict__ Xout,
    float* __restrict__ ydst, int tstep, int swz) {
  __shared__ __align__(16) h16 As[2][32 * 64];
  __shared__ __align__(16) h16 Bs[2][128 * 64];
  __shared__ float lgs[32 * 132];
  const int tid = threadIdx.x;
  const int lane = tid & 63;
  const int w = tid >> 6;
  const int rs = w & 1, ch = w >> 1;
  const int arow = lane & 15, khi = lane >> 4;
  const int x7 = arow & 7;

  int bid = blockIdx.x;
  int m0;
  if (swz) {
    int g = bid & 7, k = bid >> 3;
    m0 = (g + 8 * (k & 3)) * 256 + (k >> 2) * 32;
  } else {
    m0 = bid * 32;
  }

  auto stageA = [&](int slot, int kt) {
    int rowbase = w * 8;
    int gc = (lane & 7) ^ (lane >> 3);
    int row = rowbase + (lane >> 3);
    gload16(A + (size_t)(m0 + row) * lda + kt * 64 + gc * 8,
            &As[slot][rowbase * 64]);
  };
  auto stageB = [&](int slot, int kt) {
#pragma unroll
    for (int li = 0; li < 4; ++li) {
      int rowbase = li * 32 + w * 8;
      int row = rowbase + (lane >> 3);
      int gc = (lane & 7) ^ (lane >> 3);
      gload16(Bt + (size_t)row * 512 + kt * 64 + gc * 8, &Bs[slot][rowbase * 64]);
    }
  };

  f32x4 acc[4];
#pragma unroll
  for (int j = 0; j < 4; ++j) acc[j] = (f32x4)0.f;

  stageA(0, 0);
  stageB(0, 0);
#pragma unroll 1
  for (int kt = 0; kt < nkt; ++kt) {
    int p = kt & 1;
    if (kt + 1 < nkt) {
      stageA(p ^ 1, kt + 1);
      stageB(p ^ 1, kt + 1);
      asm volatile("s_waitcnt vmcnt(5)" ::: "memory");
    } else {
      asm volatile("s_waitcnt vmcnt(0)" ::: "memory");
    }
    ENDBAR();
#pragma unroll
    for (int kk = 0; kk < 2; ++kk) {
      int kc = kk * 4 + khi;
      int ra = rs * 16 + arow;
      f16x8 afr = *(const f16x8*)&As[p][ra * 64 + (kc ^ x7) * 8];
#pragma unroll
      for (int j = 0; j < 4; ++j) {
        int rb = (ch * 4 + j) * 16 + arow;
        f16x8 bfr = *(const f16x8*)&Bs[p][rb * 64 + (kc ^ x7) * 8];
        acc[j] = __builtin_amdgcn_mfma_f32_16x16x32_f16(afr, bfr, acc[j], 0, 0, 0);
      }
    }
    ENDBAR();
  }

#pragma unroll
  for (int j = 0; j < 4; ++j)
#pragma unroll
    for (int r = 0; r < 4; ++r)
      lgs[(rs * 16 + khi * 4 + r) * 132 + (ch * 4 + j) * 16 + arow] = acc[j][r];
  __syncthreads();
  {
    int row = tid >> 3, g8 = tid & 7;
    float v[16];
    float mx = -1e30f;
#pragma unroll
    for (int q = 0; q < 16; ++q) {
      int col = g8 * 16 + q;
      v[q] = lgs[row * 132 + col] + bias[col];
      if (col != 127) mx = fmaxf(mx, v[q]);
    }
#pragma unroll
    for (int s = 1; s < 8; s <<= 1) mx = fmaxf(mx, __shfl_xor(mx, s, 8));
    float sm = 0.f;
#pragma unroll
    for (int q = 0; q < 16; ++q) {
      int col = g8 * 16 + q;
      if (col != 127) sm += __expf(v[q] - mx);
    }
#pragma unroll
    for (int s = 1; s < 8; s <<= 1) sm += __shfl_xor(sm, s, 8);
    float inv = 1.f / sm;
    h16 xo[16];
    float yo[16];
#pragma unroll
    for (int q = 0; q < 16; ++q) {
      int col = g8 * 16 + q;
      float res = (col == 127) ? sigm(v[q]) : __expf(v[q] - mx) * inv;
      xo[q] = (h16)res;
      yo[q] = res;
    }
    h16* xd = Xout + (size_t)(m0 + row) * 640 + g8 * 16;
    *(f16x8*)xd = *(f16x8*)&xo[0];
    *(f16x8*)(xd + 8) = *(f16x8*)&xo[8];
    if (ydst) {
      float* yd = ydst + ((size_t)(m0 + row) * 64 + tstep) * 128 + g8 * 16;
#pragma unroll
      for (int q = 0; q < 4; ++q) *(f32x4*)(yd + 4 * q) = *(f32x4*)&yo[4 * q];
    }
  }
}

// ---------------------------------------------------------------------------
// Encoder GEMM (verified round-1 structure, 128x128 tile)
// ---------------------------------------------------------------------------
enum { EP_LRELU = 0, EP_LIN16 = 1, EP_F32 = 2 };

template <int EP>
__global__ __launch_bounds__(256) void gemm128(
    const h16* __restrict__ A, int lda, const h16* __restrict__ Bt,
    const float* __restrict__ bias, int K, h16* __restrict__ out16, int ldo,
    int ocol, float* __restrict__ outf, int ldf) {
  __shared__ __align__(16) h16 As[128 * 64];
  __shared__ __align__(16) h16 Bs[128 * 64];
  const int tid = threadIdx.x;
  const int lane = tid & 63;
  const int w = tid >> 6;
  const int m0 = blockIdx.x * 128;
  const int n0 = blockIdx.y * 128;

  f32x4 acc[4][4];
#pragma unroll
  for (int i = 0; i < 4; ++i)
#pragma unroll
    for (int jj = 0; jj < 4; ++jj) acc[i][jj] = (f32x4)0.f;

  const int rh = (w >> 1) * 64;
  const int arow = lane & 15;
  const int khi = lane >> 4;

  const int nkt = K >> 6;
  for (int kt = 0; kt < nkt; ++kt) {
#pragma unroll
    for (int li = 0; li < 4; ++li) {
      int L = w * 4 + li;
      int r = L * 8 + (lane >> 3);
      int c = lane & 7;
      int gc = c ^ (r & 7);
      gload16(A + (size_t)(m0 + r) * lda + kt * 64 + gc * 8, &As[L * 512]);
      gload16(Bt + (size_t)(n0 + r) * K + kt * 64 + gc * 8, &Bs[L * 512]);
    }
    __syncthreads();
#pragma unroll
    for (int kk = 0; kk < 2; ++kk) {
      const int kc = kk * 4 + khi;
      f16x8 af[4], bf[4];
#pragma unroll
      for (int mt = 0; mt < 4; ++mt) {
        int r = rh + mt * 16 + arow;
        af[mt] = *(const f16x8*)&As[r * 64 + (kc ^ (r & 7)) * 8];
      }
#pragma unroll
      for (int jj = 0; jj < 4; ++jj) {
        int nt = (w & 1) * 4 + jj;
        int r = nt * 16 + arow;
        bf[jj] = *(const f16x8*)&Bs[r * 64 + (kc ^ (r & 7)) * 8];
      }
#pragma unroll
      for (int mt = 0; mt < 4; ++mt)
#pragma unroll
        for (int jj = 0; jj < 4; ++jj)
          acc[mt][jj] =
              __builtin_amdgcn_mfma_f32_16x16x32_f16(af[mt], bf[jj], acc[mt][jj], 0, 0, 0);
    }
    __syncthreads();
  }

#pragma unroll
  for (int mt = 0; mt < 4; ++mt) {
#pragma unroll
    for (int jj = 0; jj < 4; ++jj) {
      int nt = (w & 1) * 4 + jj;
      int n = n0 + nt * 16 + arow;
      float bv = bias[n];
#pragma unroll
      for (int r = 0; r < 4; ++r) {
        int m = m0 + rh + mt * 16 + khi * 4 + r;
        float v = acc[mt][jj][r] + bv;
        if constexpr (EP == EP_LRELU) {
          v = v >= 0.f ? v : 0.2f * v;
          out16[(size_t)m * ldo + n] = (h16)v;
        } else if constexpr (EP == EP_LIN16) {
          out16[(size_t)m * ldo + ocol + n] = (h16)v;
        } else {
          outf[(size_t)m * ldf + n] = v;
        }
      }
    }
  }
}

// ---------------- prep kernels ----------------
__global__ void cvt16(const float* __restrict__ in, h16* __restrict__ out, int n) {
  int i = blockIdx.x * 256 + threadIdx.x;
  if (i < n) out[i] = (h16)in[i];
}

__global__ void transposeW(const float* __restrict__ W, h16* __restrict__ WT, int K,
                           int N) {
  int i = blockIdx.x * 256 + threadIdx.x;
  if (i >= K * N) return;
  int k = i / N, n = i % N;
  WT[(size_t)n * K + k] = (h16)W[i];
}

// WgT[n'][640]: n' = by*256 + wc*64 + q*16 + jj -> orig = q*512 + by*64 + wc*16 + jj
__global__ void prep_gate(const float* __restrict__ Wih, const float* __restrict__ Whh,
                          const float* __restrict__ bih, const float* __restrict__ bhh,
                          h16* __restrict__ WgT, float* __restrict__ bg) {
  int i = blockIdx.x * 256 + threadIdx.x;
  if (i >= 2048 * 640) return;
  int np = i / 640, k = i % 640;
  int by = np >> 8, wcc = (np >> 6) & 3, q = (np >> 4) & 3, jj = np & 15;
  int orig = q * 512 + by * 64 + wcc * 16 + jj;
  float wv = (k < 128) ? Wih[(size_t)k * 2048 + orig]
                       : Whh[(size_t)(k - 128) * 2048 + orig];
  WgT[i] = (h16)wv;
  if (k == 0) bg[np] = bih[orig] + bhh[orig];
}

// ---------------- launch ----------------
extern "C" void kernel_launch(void* const* d_in, const int* in_sizes, int n_in,
                              void* d_out, int out_size, void* d_ws, size_t ws_size,
                              hipStream_t stream) {
  const float* x = (const float*)d_in[0];
  const float* W1 = (const float*)d_in[1];
  const float* b1 = (const float*)d_in[2];
  const float* W2 = (const float*)d_in[3];
  const float* b2 = (const float*)d_in[4];
  const float* W3 = (const float*)d_in[5];
  const float* b3 = (const float*)d_in[6];
  const float* Wh1 = (const float*)d_in[7];
  const float* bh1 = (const float*)d_in[8];
  const float* Wh2 = (const float*)d_in[9];
  const float* bh2 = (const float*)d_in[10];
  const float* Wc1 = (const float*)d_in[11];
  const float* bc1 = (const float*)d_in[12];
  const float* Wc2 = (const float*)d_in[13];
  const float* bc2 = (const float*)d_in[14];
  const float* Wx1 = (const float*)d_in[15];
  const float* bx1 = (const float*)d_in[16];
  const float* Wx2 = (const float*)d_in[17];
  const float* bx2 = (const float*)d_in[18];
  const float* Wih = (const float*)d_in[19];
  const float* bih = (const float*)d_in[20];
  const float* Whh = (const float*)d_in[21];
  const float* bhh = (const float*)d_in[22];
  const float* Wp = (const float*)d_in[23];
  const float* bp = (const float*)d_in[24];

  char* ws = (char*)d_ws;
  size_t off = 0;
  auto take = [&](size_t bytes) -> void* {
    void* p = ws + off;
    off += (bytes + 255) & ~(size_t)255;
    return p;
  };
  h16* X16 = (h16*)take((size_t)BB * 256 * 2);
  h16* Za = (h16*)take((size_t)BB * 512 * 2);
  h16* Zb = (h16*)take((size_t)BB * 512 * 2);
  h16* XHa = (h16*)take((size_t)BB * 640 * 2);
  h16* XHb = (h16*)take((size_t)BB * 640 * 2);
  float* C = (float*)take((size_t)BB * 512 * 4);
  h16* W1T = (h16*)take(256 * 512 * 2);
  h16* W2T = (h16*)take(512 * 512 * 2);
  h16* W3T = (h16*)take(512 * 512 * 2);
  h16* Wh1T = (h16*)take(512 * 512 * 2);
  h16* Wh2T = (h16*)take(512 * 512 * 2);
  h16* Wc1T = (h16*)take(512 * 512 * 2);
  h16* Wc2T = (h16*)take(512 * 512 * 2);
  h16* Wx1T = (h16*)take(512 * 512 * 2);
  h16* Wx2T = (h16*)take(128 * 512 * 2);
  h16* WpT = (h16*)take(128 * 512 * 2);
  h16* WgT = (h16*)take((size_t)2048 * 640 * 2);
  float* bg = (float*)take(2048 * 4);

  dim3 blk(256);
  cvt16<<<(BB * 256 + 255) / 256, blk, 0, stream>>>(x, X16, BB * 256);
  transposeW<<<(256 * 512 + 255) / 256, blk, 0, stream>>>(W1, W1T, 256, 512);
  transposeW<<<(512 * 512 + 255) / 256, blk, 0, stream>>>(W2, W2T, 512, 512);
  transposeW<<<(512 * 512 + 255) / 256, blk, 0, stream>>>(W3, W3T, 512, 512);
  transposeW<<<(512 * 512 + 255) / 256, blk, 0, stream>>>(Wh1, Wh1T, 512, 512);
  transposeW<<<(512 * 512 + 255) / 256, blk, 0, stream>>>(Wh2, Wh2T, 512, 512);
  transposeW<<<(512 * 512 + 255) / 256, blk, 0, stream>>>(Wc1, Wc1T, 512, 512);
  transposeW<<<(512 * 512 + 255) / 256, blk, 0, stream>>>(Wc2, Wc2T, 512, 512);
  transposeW<<<(512 * 512 + 255) / 256, blk, 0, stream>>>(Wx1, Wx1T, 512, 512);
  transposeW<<<(512 * 128 + 255) / 256, blk, 0, stream>>>(Wx2, Wx2T, 512, 128);
  transposeW<<<(512 * 128 + 255) / 256, blk, 0, stream>>>(Wp, WpT, 512, 128);
  prep_gate<<<(2048 * 640 + 255) / 256, blk, 0, stream>>>(Wih, Whh, bih, bhh, WgT, bg);

  // MLP encoder
  gemm128<EP_LRELU><<<dim3(64, 4), blk, 0, stream>>>(X16, 256, W1T, b1, 256, Za, 512, 0, nullptr, 0);
  gemm128<EP_LRELU><<<dim3(64, 4), blk, 0, stream>>>(Za, 512, W2T, b2, 512, Zb, 512, 0, nullptr, 0);
  gemm128<EP_LRELU><<<dim3(64, 4), blk, 0, stream>>>(Zb, 512, W3T, b3, 512, Za, 512, 0, nullptr, 0);
  gemm128<EP_LRELU><<<dim3(64, 4), blk, 0, stream>>>(Za, 512, Wh1T, bh1, 512, Zb, 512, 0, nullptr, 0);
  gemm128<EP_LIN16><<<dim3(64, 4), blk, 0, stream>>>(Zb, 512, Wh2T, bh2, 512, XHa, 640, 128, nullptr, 0);
  gemm128<EP_LRELU><<<dim3(64, 4), blk, 0, stream>>>(Za, 512, Wc1T, bc1, 512, Zb, 512, 0, nullptr, 0);
  gemm128<EP_F32><<<dim3(64, 4), blk, 0, stream>>>(Zb, 512, Wc2T, bc2, 512, nullptr, 0, 0, C, 512);
  gemm128<EP_LRELU><<<dim3(64, 4), blk, 0, stream>>>(Za, 512, Wx1T, bx1, 512, Zb, 512, 0, nullptr, 0);
  head256<<<256, blk, 0, stream>>>(Zb, 512, Wx2T, bx2, 8, XHa, nullptr, 0, 0);

  // LSTM decoder: per-step gate + full-machine head (verified lockstep macro)
  float* yout = (float*)d_out;
  for (int t = 0; t < TT; ++t) {
    h16* in_ = (t & 1) ? XHb : XHa;
    h16* out_ = (t & 1) ? XHa : XHb;
    gate2<<<dim3(32, 8), dim3(512), 0, stream>>>(in_, WgT, bg, C, out_);
    head256<<<256, blk, 0, stream>>>(out_ + 128, 640, WpT, bp, 8, out_, yout, t, 1);
  }
}

// Round 12
// 2738.376 us; speedup vs baseline: 1.8090x; 1.8090x over previous
//
#include <hip/hip_runtime.h>

// ---------------------------------------------------------------------------
// LinearDecoder: MLP encoder -> 64-step LSTM decoder with softmax/sigmoid head
// B=8192, LAT=256, MLP=512, HID=512, INP=128, T=64, gates N=2048, K=640
// R10 macro-structure (verified 2744us): per-step gate4 + head256, lockstep.
// R12: gate4's mid-phase barrier relaxed to raw s_barrier (no forced
// lgkmcnt(0) drain / sched_barrier) -- compiler-generated ds_reads carry
// their own fine-grained lgkm waits, letting MFMA issue overlap LDS returns.
// ---------------------------------------------------------------------------

typedef _Float16 h16;
typedef __attribute__((ext_vector_type(8))) _Float16 f16x8;
typedef __attribute__((ext_vector_type(4))) float f32x4;

#define BB 8192
#define TT 64

__device__ __forceinline__ void gload16(const void* g, void* lds) {
  __builtin_amdgcn_global_load_lds(
      (const __attribute__((address_space(1))) unsigned int*)g,
      (__attribute__((address_space(3))) unsigned int*)lds, 16, 0, 0);
}

__device__ __forceinline__ float sigm(float x) { return 1.f / (1.f + __expf(-x)); }
__device__ __forceinline__ float tanhf_(float x) { return 2.f / (1.f + __expf(-2.f * x)) - 1.f; }

// raw barrier + compiler reorder fence (no forced lgkm drain)
#define RAWBAR()                                           \
  do {                                                     \
    __builtin_amdgcn_s_barrier();                          \
    asm volatile("" ::: "memory");                         \
  } while (0)
#define ENDBAR() RAWBAR()

// ---------------------------------------------------------------------------
// gate4: 4-phase 256x256 gate GEMM + fused LSTM cell update (R10 winner,
// with relaxed mid-phase barrier).
// A = XH [8192][640] fp16; Bt = WgT [2048][640] (permuted); K=640 (10 K-tiles).
// Gate col permutation: n' = by*256 + wc*64 + q*16 + jj
//                       orig = q*512 + (by*64 + wc*16 + jj)
// vmcnt guards (verified R10): Q2/Q4 vmcnt(6) pre-barrier; drain at i=4.
// ---------------------------------------------------------------------------
__global__ __launch_bounds__(512, 2) void gate4(
    const h16* __restrict__ A, const h16* __restrict__ Bt,
    const float* __restrict__ bg, float* __restrict__ Cbuf,
    h16* __restrict__ Hout) {
  __shared__ __align__(16) h16 As[2][16384];
  __shared__ __align__(16) h16 Bs[2][16384];
  const int tid = threadIdx.x;
  const int lane = tid & 63;
  const int wid = tid >> 6;
  const int wr = wid >> 2, wc = wid & 3;
  const int m0 = blockIdx.x * 256;
  const int n0 = blockIdx.y * 256;
  const int arow = lane & 15, khi = lane >> 4;
  const int x7 = arow & 7;

  auto stage = [&](h16(*dst)[16384], int slot, int h, const h16* src, int base,
                   int kt) {
#pragma unroll
    for (int li = 0; li < 2; ++li) {
      int rowbase = li * 128 + h * 64 + wid * 8;  // wave-uniform
      int row = rowbase + (lane >> 3);
      int gc = (lane & 7) ^ (lane >> 3);
      gload16(src + (size_t)(base + row) * 640 + kt * 64 + gc * 8,
              &dst[slot][rowbase * 64]);
    }
  };

  f32x4 acc[8][4];
#pragma unroll
  for (int i = 0; i < 8; ++i)
#pragma unroll
    for (int jj = 0; jj < 4; ++jj) acc[i][jj] = (f32x4)0.f;
  f16x8 af[2][4], bf[2][4];

  // read A-frags for (slot, ms) for BOTH ks into af[ks][mr]
  auto readA2 = [&](int slot, int ms) {
#pragma unroll
    for (int ks = 0; ks < 2; ++ks)
#pragma unroll
      for (int mr = 0; mr < 4; ++mr) {
        int r = wr * 128 + ms * 64 + mr * 16 + arow;
        af[ks][mr] = *(const f16x8*)&As[slot][r * 64 + ((ks * 4 + khi) ^ x7) * 8];
      }
  };
  auto readB = [&](int slot, int ks) {
#pragma unroll
    for (int jj = 0; jj < 4; ++jj) {
      int rb = wc * 64 + jj * 16 + arow;
      bf[ks][jj] = *(const f16x8*)&Bs[slot][rb * 64 + ((ks * 4 + khi) ^ x7) * 8];
    }
  };
  auto mfma32 = [&](int ms) {
    __builtin_amdgcn_s_setprio(1);
#pragma unroll
    for (int ks = 0; ks < 2; ++ks)
#pragma unroll
      for (int mr = 0; mr < 4; ++mr)
#pragma unroll
        for (int jj = 0; jj < 4; ++jj)
          acc[ms * 4 + mr][jj] = __builtin_amdgcn_mfma_f32_16x16x32_f16(
              af[ks][mr], bf[ks][jj], acc[ms * 4 + mr][jj], 0, 0, 0);
    __builtin_amdgcn_s_setprio(0);
  };

  // prologue: kt0 fully, kt1 all but A-h1 (14 loads; vmcnt(6) -> slot0 done)
  stage(Bs, 0, 0, Bt, n0, 0);
  stage(Bs, 0, 1, Bt, n0, 0);
  stage(As, 0, 0, A, m0, 0);
  stage(As, 0, 1, A, m0, 0);
  stage(Bs, 1, 0, Bt, n0, 1);
  stage(Bs, 1, 1, Bt, n0, 1);
  stage(As, 1, 0, A, m0, 1);
  asm volatile("s_waitcnt vmcnt(6)" ::: "memory");
  ENDBAR();

#pragma unroll 1
  for (int i = 0; i < 5; ++i) {
    const int t2 = 2 * i + 2, t3 = 2 * i + 3;
    // Q1: slot0 ms0, both ks; stage A1h1(2i+1), B0h0(t2)
    readB(0, 0);
    readB(0, 1);
    readA2(0, 0);
    stage(As, 1, 1, A, m0, 2 * i + 1);
    if (t2 < 10) stage(Bs, 0, 0, Bt, n0, t2);
    RAWBAR();
    mfma32(0);
    ENDBAR();
    // Q2: slot0 ms1; stage B0h1(t2), A0h0(t2); guard slot1
    readA2(0, 1);
    if (t2 < 10) {
      stage(Bs, 0, 1, Bt, n0, t2);
      stage(As, 0, 0, A, m0, t2);
    }
    if (i < 4)
      asm volatile("s_waitcnt vmcnt(6)" ::: "memory");
    else
      asm volatile("s_waitcnt vmcnt(0)" ::: "memory");
    RAWBAR();
    mfma32(1);
    ENDBAR();
    // Q3: slot1 ms0, both ks; stage A0h1(t2), B1h0(t3)
    readB(1, 0);
    readB(1, 1);
    readA2(1, 0);
    if (t2 < 10) stage(As, 0, 1, A, m0, t2);
    if (t3 < 10) stage(Bs, 1, 0, Bt, n0, t3);
    RAWBAR();
    mfma32(0);
    ENDBAR();
    // Q4: slot1 ms1; stage B1h1(t3), A1h0(t3); guard slot0
    readA2(1, 1);
    if (t3 < 10) {
      stage(Bs, 1, 1, Bt, n0, t3);
      stage(As, 1, 0, A, m0, t3);
    }
    if (i < 4)
      asm volatile("s_waitcnt vmcnt(6)" ::: "memory");
    else
      asm volatile("s_waitcnt vmcnt(0)" ::: "memory");
    RAWBAR();
    mfma32(1);
    ENDBAR();
  }

  // ---- gate epilogue: LSTM cell update ----
  const int nb = n0 + wc * 64;
  const float bI = bg[nb + arow];
  const float bF = bg[nb + 16 + arow];
  const float bG = bg[nb + 32 + arow];
  const float bO = bg[nb + 48 + arow];
  const int hj = blockIdx.y * 64 + wc * 16 + arow;
#pragma unroll
  for (int mrep = 0; mrep < 8; ++mrep) {
#pragma unroll
    for (int r = 0; r < 4; ++r) {
      int m = m0 + wr * 128 + mrep * 16 + khi * 4 + r;
      float gi = sigm(acc[mrep][0][r] + bI);
      float gf = sigm(acc[mrep][1][r] + bF);
      float gg = tanhf_(acc[mrep][2][r] + bG);
      float go = sigm(acc[mrep][3][r] + bO);
      size_t ci = (size_t)m * 512 + hj;
      float c2 = gf * Cbuf[ci] + gi * gg;
      Cbuf[ci] = c2;
      Hout[(size_t)m * 640 + 128 + hj] = (h16)(go * tanhf_(c2));
    }
  }
}

// ---------------------------------------------------------------------------
// head256: full-machine head. 256 blocks x 32 rows, 256 thr (4 waves).
// Verified R8 kernel. swz aligns block's XCD (bid%8) with h-writer XCD (mx%8).
// ---------------------------------------------------------------------------
__global__ __launch_bounds__(256) void head256(
    const h16* __restrict__ A, int lda, const h16* __restrict__ Bt,
    const float* __restrict__ bias, int nkt, h16* __restrict__ Xout,
    float* __restrict__ ydst, int tstep, int swz) {
  __shared__ __align__(16) h16 As[2][32 * 64];
  __shared__ __align__(16) h16 Bs[2][128 * 64];
  __shared__ float lgs[32 * 132];
  const int tid = threadIdx.x;
  const int lane = tid & 63;
  const int w = tid >> 6;
  const int rs = w & 1, ch = w >> 1;
  const int arow = lane & 15, khi = lane >> 4;
  const int x7 = arow & 7;

  int bid = blockIdx.x;
  int m0;
  if (swz) {
    int g = bid & 7, k = bid >> 3;
    m0 = (g + 8 * (k & 3)) * 256 + (k >> 2) * 32;
  } else {
    m0 = bid * 32;
  }

  auto stageA = [&](int slot, int kt) {
    int rowbase = w * 8;
    int gc = (lane & 7) ^ (lane >> 3);
    int row = rowbase + (lane >> 3);
    gload16(A + (size_t)(m0 + row) * lda + kt * 64 + gc * 8,
            &As[slot][rowbase * 64]);
  };
  auto stageB = [&](int slot, int kt) {
#pragma unroll
    for (int li = 0; li < 4; ++li) {
      int rowbase = li * 32 + w * 8;
      int row = rowbase + (lane >> 3);
      int gc = (lane & 7) ^ (lane >> 3);
      gload16(Bt + (size_t)row * 512 + kt * 64 + gc * 8, &Bs[slot][rowbase * 64]);
    }
  };

  f32x4 acc[4];
#pragma unroll
  for (int j = 0; j < 4; ++j) acc[j] = (f32x4)0.f;

  stageA(0, 0);
  stageB(0, 0);
#pragma unroll 1
  for (int kt = 0; kt < nkt; ++kt) {
    int p = kt & 1;
    if (kt + 1 < nkt) {
      stageA(p ^ 1, kt + 1);
      stageB(p ^ 1, kt + 1);
      asm volatile("s_waitcnt vmcnt(5)" ::: "memory");
    } else {
      asm volatile("s_waitcnt vmcnt(0)" ::: "memory");
    }
    ENDBAR();
#pragma unroll
    for (int kk = 0; kk < 2; ++kk) {
      int kc = kk * 4 + khi;
      int ra = rs * 16 + arow;
      f16x8 afr = *(const f16x8*)&As[p][ra * 64 + (kc ^ x7) * 8];
#pragma unroll
      for (int j = 0; j < 4; ++j) {
        int rb = (ch * 4 + j) * 16 + arow;
        f16x8 bfr = *(const f16x8*)&Bs[p][rb * 64 + (kc ^ x7) * 8];
        acc[j] = __builtin_amdgcn_mfma_f32_16x16x32_f16(afr, bfr, acc[j], 0, 0, 0);
      }
    }
    ENDBAR();
  }

#pragma unroll
  for (int j = 0; j < 4; ++j)
#pragma unroll
    for (int r = 0; r < 4; ++r)
      lgs[(rs * 16 + khi * 4 + r) * 132 + (ch * 4 + j) * 16 + arow] = acc[j][r];
  __syncthreads();
  {
    int row = tid >> 3, g8 = tid & 7;
    float v[16];
    float mx = -1e30f;
#pragma unroll
    for (int q = 0; q < 16; ++q) {
      int col = g8 * 16 + q;
      v[q] = lgs[row * 132 + col] + bias[col];
      if (col != 127) mx = fmaxf(mx, v[q]);
    }
#pragma unroll
    for (int s = 1; s < 8; s <<= 1) mx = fmaxf(mx, __shfl_xor(mx, s, 8));
    float sm = 0.f;
#pragma unroll
    for (int q = 0; q < 16; ++q) {
      int col = g8 * 16 + q;
      if (col != 127) sm += __expf(v[q] - mx);
    }
#pragma unroll
    for (int s = 1; s < 8; s <<= 1) sm += __shfl_xor(sm, s, 8);
    float inv = 1.f / sm;
    h16 xo[16];
    float yo[16];
#pragma unroll
    for (int q = 0; q < 16; ++q) {
      int col = g8 * 16 + q;
      float res = (col == 127) ? sigm(v[q]) : __expf(v[q] - mx) * inv;
      xo[q] = (h16)res;
      yo[q] = res;
    }
    h16* xd = Xout + (size_t)(m0 + row) * 640 + g8 * 16;
    *(f16x8*)xd = *(f16x8*)&xo[0];
    *(f16x8*)(xd + 8) = *(f16x8*)&xo[8];
    if (ydst) {
      float* yd = ydst + ((size_t)(m0 + row) * 64 + tstep) * 128 + g8 * 16;
#pragma unroll
      for (int q = 0; q < 4; ++q) *(f32x4*)(yd + 4 * q) = *(f32x4*)&yo[4 * q];
    }
  }
}

// ---------------------------------------------------------------------------
// Encoder GEMM (verified round-1 structure, 128x128 tile)
// ---------------------------------------------------------------------------
enum { EP_LRELU = 0, EP_LIN16 = 1, EP_F32 = 2 };

template <int EP>
__global__ __launch_bounds__(256) void gemm128(
    const h16* __restrict__ A, int lda, const h16* __restrict__ Bt,
    const float* __restrict__ bias, int K, h16* __restrict__ out16, int ldo,
    int ocol, float* __restrict__ outf, int ldf) {
  __shared__ __align__(16) h16 As[128 * 64];
  __shared__ __align__(16) h16 Bs[128 * 64];
  const int tid = threadIdx.x;
  const int lane = tid & 63;
  const int w = tid >> 6;
  const int m0 = blockIdx.x * 128;
  const int n0 = blockIdx.y * 128;

  f32x4 acc[4][4];
#pragma unroll
  for (int i = 0; i < 4; ++i)
#pragma unroll
    for (int jj = 0; jj < 4; ++jj) acc[i][jj] = (f32x4)0.f;

  const int rh = (w >> 1) * 64;
  const int arow = lane & 15;
  const int khi = lane >> 4;

  const int nkt = K >> 6;
  for (int kt = 0; kt < nkt; ++kt) {
#pragma unroll
    for (int li = 0; li < 4; ++li) {
      int L = w * 4 + li;
      int r = L * 8 + (lane >> 3);
      int c = lane & 7;
      int gc = c ^ (r & 7);
      gload16(A + (size_t)(m0 + r) * lda + kt * 64 + gc * 8, &As[L * 512]);
      gload16(Bt + (size_t)(n0 + r) * K + kt * 64 + gc * 8, &Bs[L * 512]);
    }
    __syncthreads();
#pragma unroll
    for (int kk = 0; kk < 2; ++kk) {
      const int kc = kk * 4 + khi;
      f16x8 af[4], bf[4];
#pragma unroll
      for (int mt = 0; mt < 4; ++mt) {
        int r = rh + mt * 16 + arow;
        af[mt] = *(const f16x8*)&As[r * 64 + (kc ^ (r & 7)) * 8];
      }
#pragma unroll
      for (int jj = 0; jj < 4; ++jj) {
        int nt = (w & 1) * 4 + jj;
        int r = nt * 16 + arow;
        bf[jj] = *(const f16x8*)&Bs[r * 64 + (kc ^ (r & 7)) * 8];
      }
#pragma unroll
      for (int mt = 0; mt < 4; ++mt)
#pragma unroll
        for (int jj = 0; jj < 4; ++jj)
          acc[mt][jj] =
              __builtin_amdgcn_mfma_f32_16x16x32_f16(af[mt], bf[jj], acc[mt][jj], 0, 0, 0);
    }
    __syncthreads();
  }

#pragma unroll
  for (int mt = 0; mt < 4; ++mt) {
#pragma unroll
    for (int jj = 0; jj < 4; ++jj) {
      int nt = (w & 1) * 4 + jj;
      int n = n0 + nt * 16 + arow;
      float bv = bias[n];
#pragma unroll
      for (int r = 0; r < 4; ++r) {
        int m = m0 + rh + mt * 16 + khi * 4 + r;
        float v = acc[mt][jj][r] + bv;
        if constexpr (EP == EP_LRELU) {
          v = v >= 0.f ? v : 0.2f * v;
          out16[(size_t)m * ldo + n] = (h16)v;
        } else if constexpr (EP == EP_LIN16) {
          out16[(size_t)m * ldo + ocol + n] = (h16)v;
        } else {
          outf[(size_t)m * ldf + n] = v;
        }
      }
    }
  }
}

// ---------------- prep kernels ----------------
__global__ void cvt16(const float* __restrict__ in, h16* __restrict__ out, int n) {
  int i = blockIdx.x * 256 + threadIdx.x;
  if (i < n) out[i] = (h16)in[i];
}

__global__ void transposeW(const float* __restrict__ W, h16* __restrict__ WT, int K,
                           int N) {
  int i = blockIdx.x * 256 + threadIdx.x;
  if (i >= K * N) return;
  int k = i / N, n = i % N;
  WT[(size_t)n * K + k] = (h16)W[i];
}

// WgT[n'][640]: n' = by*256 + wc*64 + q*16 + jj -> orig = q*512 + by*64 + wc*16 + jj
__global__ void prep_gate(const float* __restrict__ Wih, const float* __restrict__ Whh,
                          const float* __restrict__ bih, const float* __restrict__ bhh,
                          h16* __restrict__ WgT, float* __restrict__ bg) {
  int i = blockIdx.x * 256 + threadIdx.x;
  if (i >= 2048 * 640) return;
  int np = i / 640, k = i % 640;
  int by = np >> 8, wcc = (np >> 6) & 3, q = (np >> 4) & 3, jj = np & 15;
  int orig = q * 512 + by * 64 + wcc * 16 + jj;
  float wv = (k < 128) ? Wih[(size_t)k * 2048 + orig]
                       : Whh[(size_t)(k - 128) * 2048 + orig];
  WgT[i] = (h16)wv;
  if (k == 0) bg[np] = bih[orig] + bhh[orig];
}

// ---------------- launch ----------------
extern "C" void kernel_launch(void* const* d_in, const int* in_sizes, int n_in,
                              void* d_out, int out_size, void* d_ws, size_t ws_size,
                              hipStream_t stream) {
  const float* x = (const float*)d_in[0];
  const float* W1 = (const float*)d_in[1];
  const float* b1 = (const float*)d_in[2];
  const float* W2 = (const float*)d_in[3];
  const float* b2 = (const float*)d_in[4];
  const float* W3 = (const float*)d_in[5];
  const float* b3 = (const float*)d_in[6];
  const float* Wh1 = (const float*)d_in[7];
  const float* bh1 = (const float*)d_in[8];
  const float* Wh2 = (const float*)d_in[9];
  const float* bh2 = (const float*)d_in[10];
  const float* Wc1 = (const float*)d_in[11];
  const float* bc1 = (const float*)d_in[12];
  const float* Wc2 = (const float*)d_in[13];
  const float* bc2 = (const float*)d_in[14];
  const float* Wx1 = (const float*)d_in[15];
  const float* bx1 = (const float*)d_in[16];
  const float* Wx2 = (const float*)d_in[17];
  const float* bx2 = (const float*)d_in[18];
  const float* Wih = (const float*)d_in[19];
  const float* bih = (const float*)d_in[20];
  const float* Whh = (const float*)d_in[21];
  const float* bhh = (const float*)d_in[22];
  const float* Wp = (const float*)d_in[23];
  const float* bp = (const float*)d_in[24];

  char* ws = (char*)d_ws;
  size_t off = 0;
  auto take = [&](size_t bytes) -> void* {
    void* p = ws + off;
    off += (bytes + 255) & ~(size_t)255;
    return p;
  };
  h16* X16 = (h16*)take((size_t)BB * 256 * 2);
  h16* Za = (h16*)take((size_t)BB * 512 * 2);
  h16* Zb = (h16*)take((size_t)BB * 512 * 2);
  h16* XHa = (h16*)take((size_t)BB * 640 * 2);
  h16* XHb = (h16*)take((size_t)BB * 640 * 2);
  float* C = (float*)take((size_t)BB * 512 * 4);
  h16* W1T = (h16*)take(256 * 512 * 2);
  h16* W2T = (h16*)take(512 * 512 * 2);
  h16* W3T = (h16*)take(512 * 512 * 2);
  h16* Wh1T = (h16*)take(512 * 512 * 2);
  h16* Wh2T = (h16*)take(512 * 512 * 2);
  h16* Wc1T = (h16*)take(512 * 512 * 2);
  h16* Wc2T = (h16*)take(512 * 512 * 2);
  h16* Wx1T = (h16*)take(512 * 512 * 2);
  h16* Wx2T = (h16*)take(128 * 512 * 2);
  h16* WpT = (h16*)take(128 * 512 * 2);
  h16* WgT = (h16*)take((size_t)2048 * 640 * 2);
  float* bg = (float*)take(2048 * 4);

  dim3 blk(256);
  cvt16<<<(BB * 256 + 255) / 256, blk, 0, stream>>>(x, X16, BB * 256);
  transposeW<<<(256 * 512 + 255) / 256, blk, 0, stream>>>(W1, W1T, 256, 512);
  transposeW<<<(512 * 512 + 255) / 256, blk, 0, stream>>>(W2, W2T, 512, 512);
  transposeW<<<(512 * 512 + 255) / 256, blk, 0, stream>>>(W3, W3T, 512, 512);
  transposeW<<<(512 * 512 + 255) / 256, blk, 0, stream>>>(Wh1, Wh1T, 512, 512);
  transposeW<<<(512 * 512 + 255) / 256, blk, 0, stream>>>(Wh2, Wh2T, 512, 512);
  transposeW<<<(512 * 512 + 255) / 256, blk, 0, stream>>>(Wc1, Wc1T, 512, 512);
  transposeW<<<(512 * 512 + 255) / 256, blk, 0, stream>>>(Wc2, Wc2T, 512, 512);
  transposeW<<<(512 * 512 + 255) / 256, blk, 0, stream>>>(Wx1, Wx1T, 512, 512);
  transposeW<<<(512 * 128 + 255) / 256, blk, 0, stream>>>(Wx2, Wx2T, 512, 128);
  transposeW<<<(512 * 128 + 255) / 256, blk, 0, stream>>>(Wp, WpT, 512, 128);
  prep_gate<<<(2048 * 640 + 255) / 256, blk, 0, stream>>>(Wih, Whh, bih, bhh, WgT, bg);

  // MLP encoder
  gemm128<EP_LRELU><<<dim3(64, 4), blk, 0, stream>>>(X16, 256, W1T, b1, 256, Za, 512, 0, nullptr, 0);
  gemm128<EP_LRELU><<<dim3(64, 4), blk, 0, stream>>>(Za, 512, W2T, b2, 512, Zb, 512, 0, nullptr, 0);
  gemm128<EP_LRELU><<<dim3(64, 4), blk, 0, stream>>>(Zb, 512, W3T, b3, 512, Za, 512, 0, nullptr, 0);
  gemm128<EP_LRELU><<<dim3(64, 4), blk, 0, stream>>>(Za, 512, Wh1T, bh1, 512, Zb, 512, 0, nullptr, 0);
  gemm128<EP_LIN16><<<dim3(64, 4), blk, 0, stream>>>(Zb, 512, Wh2T, bh2, 512, XHa, 640, 128, nullptr, 0);
  gemm128<EP_LRELU><<<dim3(64, 4), blk, 0, stream>>>(Za, 512, Wc1T, bc1, 512, Zb, 512, 0, nullptr, 0);
  gemm128<EP_F32><<<dim3(64, 4), blk, 0, stream>>>(Zb, 512, Wc2T, bc2, 512, nullptr, 0, 0, C, 512);
  gemm128<EP_LRELU><<<dim3(64, 4), blk, 0, stream>>>(Za, 512, Wx1T, bx1, 512, Zb, 512, 0, nullptr, 0);
  head256<<<256, blk, 0, stream>>>(Zb, 512, Wx2T, bx2, 8, XHa, nullptr, 0, 0);

  // LSTM decoder: per-step gate + full-machine head (verified lockstep macro)
  float* yout = (float*)d_out;
  for (int t = 0; t < TT; ++t) {
    h16* in_ = (t & 1) ? XHb : XHa;
    h16* out_ = (t & 1) ? XHa : XHb;
    gate4<<<dim3(32, 8), dim3(512), 0, stream>>>(in_, WgT, bg, C, out_);
    head256<<<256, blk, 0, stream>>>(out_ + 128, 640, WpT, bp, 8, out_, yout, t, 1);
  }
}